// Round 13
// baseline (428.802 us; speedup 1.0000x reference)
//
#include <hip/hip_runtime.h>
#include <hip/hip_bf16.h>
#include <stdint.h>

#define S_ 2048
#define D_ 1024
#define B_ 8
#define KEXP 3072            // 3 * D : [h,l,h] x [h,h,l] fp16 expansion
#define NEGC 1e9f

typedef _Float16 f16;
typedef _Float16 f16x8 __attribute__((ext_vector_type(8)));
typedef float f32x4 __attribute__((ext_vector_type(4)));

#define DSR(dst, addr, off) \
  asm volatile("ds_read_b128 %0, %1 offset:%c2" : "=v"(dst) : "v"(addr), "i"(off))
#define WAITL(n) do { asm volatile("s_waitcnt lgkmcnt(%c0)" :: "i"(n) : "memory"); \
                      __builtin_amdgcn_sched_barrier(0); } while (0)
#define VMC(n) asm volatile("s_waitcnt vmcnt(%c0)" :: "i"(n) : "memory")
#define BAR() __builtin_amdgcn_s_barrier()

// ---------------------------------------------------------------------------
// K0: split fp32 -> fp16 hi/lo 3-term expansion, input pre-scaled by 64.
// pattern A (q): [h,l,h]   pattern B (k): [h,h,l];  blockIdx.y: 0=q, 1=k.
// ---------------------------------------------------------------------------
__global__ __launch_bounds__(256) void split_expand2(const float* __restrict__ qin,
                                                     const float* __restrict__ kin,
                                                     f16* __restrict__ qx,
                                                     f16* __restrict__ kx) {
  const int isB = blockIdx.y;
  const float* in = isB ? kin : qin;
  f16* out = isB ? kx : qx;
  size_t idx = (size_t)blockIdx.x * 256 + threadIdx.x;
  const float4* ip = (const float4*)(in + idx * 8);
  float4 a = ip[0], b = ip[1];
  float vv[8] = {a.x, a.y, a.z, a.w, b.x, b.y, b.z, b.w};
  union { f16 h[24]; uint4 u[3]; } o;
#pragma unroll
  for (int t = 0; t < 8; ++t) {
    float v = vv[t] * 64.0f;
    f16 h = (f16)v;
    float r = v - (float)h;      // exact (Sterbenz)
    f16 l = (f16)r;
    o.h[3 * t + 0] = h;
    o.h[3 * t + 1] = isB ? h : l;
    o.h[3 * t + 2] = isB ? l : h;
  }
  uint4* op = (uint4*)(out + idx * 24);
  op[0] = o.u[0]; op[1] = o.u[1]; op[2] = o.u[2];
}

// ---------------------------------------------------------------------------
// K0c: khT[b][d][j] = fp16(k[b][j][d])
// ---------------------------------------------------------------------------
__global__ __launch_bounds__(256) void transpose_cast(const float* __restrict__ k,
                                                      f16* __restrict__ khT) {
  __shared__ f16 tile[64][65];
  int j0 = blockIdx.x * 64, d0 = blockIdx.y * 64;
  size_t bz = blockIdx.z;
  const float* kb = k + bz * (size_t)S_ * D_;
  f16* ob = khT + bz * (size_t)D_ * S_;
#pragma unroll
  for (int i = 0; i < 16; ++i) {
    int e = threadIdx.x + i * 256;
    int r = e >> 6, c = e & 63;
    tile[c][r] = (f16)kb[(size_t)(j0 + r) * D_ + d0 + c];
  }
  __syncthreads();
#pragma unroll
  for (int i = 0; i < 16; ++i) {
    int e = threadIdx.x + i * 256;
    int r = e >> 6, c = e & 63;
    ob[(size_t)(d0 + r) * S_ + j0 + c] = tile[r][c];
  }
}

// ---------------------------------------------------------------------------
// 8-phase GEMM (B-transposed), snake-order fragment reuse; two schedules:
// PIPE=0 (QK^T, NFQ=2): single barrier per phase (R12) + R13 half-split:
//   reads issued [k-lo half | k-hi half]; WAITL(#hi) gates the lo-MFMAs so
//   the hi reads drain IN PARALLEL with them; WAITL(0) then hi-MFMAs.
//   Per-acc-element k-order stays lo->hi (bit-identical). No extra regs.
// PIPE=1 (PV, NFQ=1): cross-phase read pipelining with counted lgkm,
//   launch_bounds(512,1); live set fits (R8-proven).
// Both: dbuf-2 LDS, ledger unchanged from R12 (proven race-free);
// absmax must stay exactly 0.03125 — race canary.
// ---------------------------------------------------------------------------
template <int KA, int NN, int BN, int PIPE>
__global__ __launch_bounds__(512, PIPE ? 1 : 2) void gemm8p(const f16* __restrict__ A,
                                                            const f16* __restrict__ Bm,
                                                            float* __restrict__ C,
                                                            const float* scale_ptr,
                                                            float factor) {
  constexpr int NFQ = BN / 128;     // B frags per phase (2 or 1)
  constexpr int GB = NFQ;           // gloads per stgB
  constexpr int NB = 2 * NFQ;       // ds_reads per B-issue
  constexpr int H2A = 4 + NFQ;      // hi-half count when A+B both read (p1/p5)
  constexpr int VP3 = 2 + GB;       // vmcnt at p3-end (PIPE)
  constexpr int VP7 = 2 + 2 * GB;   // vmcnt at p7-end (PIPE)
  constexpr int VPR = 4 + 2 * GB;   // prologue vmcnt (PIPE)
  constexpr int NI = KA / 128;      // iterations (2 K-tiles each)
  __shared__ f16 AS[2][256 * 64];   // 2 x 32KB
  __shared__ f16 BS[2][BN * 64];    // 2 x (32|16)KB

  const int tid = threadIdx.x;
  const int lane = tid & 63, wave = tid >> 6;
  const int wm = wave >> 2, wn = wave & 3;        // 2 x 4 wave grid
  const int fr = lane & 15, kq = lane >> 4;

  // XCD-chunk swizzle (bijective: grid multiple of 8)
  int lin = blockIdx.x + gridDim.x * blockIdx.y;
  int ntot = gridDim.x * gridDim.y;
  int nid = (lin & 7) * (ntot >> 3) + (lin >> 3);
  int bz = nid >> 6, rem = nid & 63;
  int bx = rem & 7, by = rem >> 3;

  const f16* Ab = A + (size_t)bz * S_ * KA + (size_t)bx * 256 * KA;
  const f16* Bb = Bm + (size_t)bz * NN * KA + (size_t)by * BN * KA;

  // fragment read bases; XOR swizzle on 16B chunks (0 conflicts, R3-R12)
  const int T0 = fr * 128 + (((0 + kq) ^ (fr & 7)) << 4);
  const int T1 = fr * 128 + (((4 + kq) ^ (fr & 7)) << 4);
  uint32_t asbase = (uint32_t)(uintptr_t)(__attribute__((address_space(3))) f16*)&AS[0][0];
  uint32_t bsbase = (uint32_t)(uintptr_t)(__attribute__((address_space(3))) f16*)&BS[0][0];
  uint32_t aA[2][2], aB[2][2];
#pragma unroll
  for (int b = 0; b < 2; ++b) {
    aA[b][0] = asbase + b * 32768 + wm * 8192 + T0;
    aA[b][1] = asbase + b * 32768 + wm * 8192 + T1;
    aB[b][0] = bsbase + b * (BN * 128) + wn * (BN * 16) + T0;
    aB[b][1] = bsbase + b * (BN * 128) + wn * (BN * 16) + T1;
  }

  // staging: linear LDS dest, inverse-swizzled global source
  const int srl = tid >> 3;
  const int sgc = ((((tid * 16) & 127) ^ (((tid >> 3) & 7) << 4)) >> 1);

  auto stgA = [&](int buf, int unit, int kt) {
#pragma unroll
    for (int i = 0; i < 2; ++i) {
      const f16* src = Ab + (size_t)(unit * 128 + i * 64 + srl) * KA + kt * 64 + sgc;
      __builtin_amdgcn_global_load_lds(
          (const __attribute__((address_space(1))) void*)src,
          (__attribute__((address_space(3))) void*)&AS[buf][unit * 8192 + i * 4096 + wave * 512],
          16, 0, 0);
    }
  };
  auto stgB = [&](int buf, int unit, int kt) {
#pragma unroll
    for (int i = 0; i < GB; ++i) {
      const f16* src = Bb + (size_t)(unit * (BN / 2) + i * 64 + srl) * KA + kt * 64 + sgc;
      __builtin_amdgcn_global_load_lds(
          (const __attribute__((address_space(1))) void*)src,
          (__attribute__((address_space(3))) void*)&BS[buf][unit * (BN * 32) + i * 4096 + wave * 512],
          16, 0, 0);
    }
  };

  f32x4 acc[2][2][4][2];
#pragma unroll
  for (int mh = 0; mh < 2; ++mh)
#pragma unroll
    for (int nh = 0; nh < 2; ++nh)
#pragma unroll
      for (int m = 0; m < 4; ++m)
#pragma unroll
        for (int n = 0; n < NFQ; ++n)
#pragma unroll
          for (int r = 0; r < 4; ++r) acc[mh][nh][m][n][r] = 0.0f;

#define ISS_A_LO(DST, UB, MH) do {               \
    DSR(DST[0], aA[UB][0], (MH)*16384 + 0);      \
    DSR(DST[1], aA[UB][0], (MH)*16384 + 2048);   \
    DSR(DST[2], aA[UB][0], (MH)*16384 + 4096);   \
    DSR(DST[3], aA[UB][0], (MH)*16384 + 6144);   \
  } while (0)

#define ISS_A_HI(DST, UB, MH) do {               \
    DSR(DST[4], aA[UB][1], (MH)*16384 + 0);      \
    DSR(DST[5], aA[UB][1], (MH)*16384 + 2048);   \
    DSR(DST[6], aA[UB][1], (MH)*16384 + 4096);   \
    DSR(DST[7], aA[UB][1], (MH)*16384 + 6144);   \
  } while (0)

#define ISS_B_LO(DST, UB, NH) do {                    \
    DSR(DST[0], aB[UB][0], (NH) * (BN * 64) + 0);     \
    if constexpr (NFQ == 2) {                         \
      DSR(DST[2], aB[UB][0], (NH) * (BN * 64) + 2048);\
    }                                                 \
  } while (0)

#define ISS_B_HI(DST, UB, NH) do {                    \
    DSR(DST[1], aB[UB][1], (NH) * (BN * 64) + 0);     \
    if constexpr (NFQ == 2) {                         \
      DSR(DST[3], aB[UB][1], (NH) * (BN * 64) + 2048);\
    }                                                 \
  } while (0)

#define ISS_A(DST, UB, MH) do { ISS_A_LO(DST, UB, MH); ISS_A_HI(DST, UB, MH); } while (0)
#define ISS_B(DST, UB, NH) do { ISS_B_LO(DST, UB, NH); ISS_B_HI(DST, UB, NH); } while (0)

#define MMX_LO(MH, NH, AF, BF) do {                                                       \
    __builtin_amdgcn_s_setprio(1);                                                        \
    _Pragma("unroll")                                                                     \
    for (int m = 0; m < 4; ++m) {                                                         \
      acc[MH][NH][m][0] = __builtin_amdgcn_mfma_f32_16x16x32_f16(AF[m], BF[0], acc[MH][NH][m][0], 0, 0, 0); \
      if constexpr (NFQ == 2)                                                             \
        acc[MH][NH][m][1] = __builtin_amdgcn_mfma_f32_16x16x32_f16(AF[m], BF[2], acc[MH][NH][m][1], 0, 0, 0); \
    }                                                                                     \
    __builtin_amdgcn_s_setprio(0);                                                        \
  } while (0)

#define MMX_HI(MH, NH, AF, BF) do {                                                       \
    __builtin_amdgcn_s_setprio(1);                                                        \
    _Pragma("unroll")                                                                     \
    for (int m = 0; m < 4; ++m) {                                                         \
      acc[MH][NH][m][0] = __builtin_amdgcn_mfma_f32_16x16x32_f16(AF[4 + m], BF[1], acc[MH][NH][m][0], 0, 0, 0); \
      if constexpr (NFQ == 2)                                                             \
        acc[MH][NH][m][1] = __builtin_amdgcn_mfma_f32_16x16x32_f16(AF[4 + m], BF[3], acc[MH][NH][m][1], 0, 0, 0); \
    }                                                                                     \
    __builtin_amdgcn_s_setprio(0);                                                        \
  } while (0)

#define MMX(MH, NH, AF, BF) do {                                                          \
    __builtin_amdgcn_s_setprio(1);                                                        \
    _Pragma("unroll")                                                                     \
    for (int m = 0; m < 4; ++m) {                                                         \
      acc[MH][NH][m][0] = __builtin_amdgcn_mfma_f32_16x16x32_f16(AF[m], BF[0], acc[MH][NH][m][0], 0, 0, 0);     \
      acc[MH][NH][m][0] = __builtin_amdgcn_mfma_f32_16x16x32_f16(AF[4 + m], BF[1], acc[MH][NH][m][0], 0, 0, 0); \
      if constexpr (NFQ == 2) {                                                           \
        acc[MH][NH][m][1] = __builtin_amdgcn_mfma_f32_16x16x32_f16(AF[m], BF[2], acc[MH][NH][m][1], 0, 0, 0);     \
        acc[MH][NH][m][1] = __builtin_amdgcn_mfma_f32_16x16x32_f16(AF[4 + m], BF[3], acc[MH][NH][m][1], 0, 0, 0); \
      }                                                                                   \
    }                                                                                     \
    __builtin_amdgcn_s_setprio(0);                                                        \
  } while (0)

  if constexpr (!PIPE) {
    // ==== serialized snake + R13 half-split (single barrier per phase) ====
    stgA(0, 0, 0); stgA(0, 1, 0); stgB(0, 0, 0); stgB(0, 1, 0);
    stgA(1, 0, 1);
    VMC(0); BAR();

#pragma unroll 1
    for (int I = 0; I < NI; ++I) {
      const int v = 2 * I + 1, u2 = 2 * I + 2, v2 = 2 * I + 3;
      const bool st = (I + 1 < NI);
      f16x8 af[8], bf[4];
      // ---- UB0 (tile u = 2I)
      // p1: fresh af + bf
      ISS_A_LO(af, 0, 0); ISS_B_LO(bf, 0, 0); ISS_A_HI(af, 0, 0); ISS_B_HI(bf, 0, 0);
      stgA(1, 1, v);
      WAITL(H2A); MMX_LO(0, 0, af, bf); WAITL(0); MMX_HI(0, 0, af, bf); BAR();
      // p2: fresh bf only (af reused)
      ISS_B_LO(bf, 0, 1); ISS_B_HI(bf, 0, 1);
      stgB(1, 0, v); stgB(1, 1, v);
      WAITL(NFQ); MMX_LO(0, 1, af, bf); WAITL(0); MMX_HI(0, 1, af, bf); BAR();
      // p3: fresh af only (bf reused)
      ISS_A_LO(af, 0, 1); ISS_A_HI(af, 0, 1);
      if (st) stgA(0, 0, u2);
      WAITL(4); MMX_LO(1, 1, af, bf); WAITL(0); MMX_HI(1, 1, af, bf); BAR();
      // p4: fresh bf (NH0 re-read)
      ISS_B_LO(bf, 0, 0); ISS_B_HI(bf, 0, 0);
      if (st) stgA(0, 1, u2);
      WAITL(NFQ); MMX_LO(1, 0, af, bf); WAITL(0); MMX_HI(1, 0, af, bf);
      if (st) { VMC(4); } else { VMC(0); }
      BAR();
      // ---- UB1 (tile v = 2I+1)
      ISS_A_LO(af, 1, 0); ISS_B_LO(bf, 1, 0); ISS_A_HI(af, 1, 0); ISS_B_HI(bf, 1, 0);
      if (st) stgB(0, 1, u2);
      WAITL(H2A); MMX_LO(0, 0, af, bf); WAITL(0); MMX_HI(0, 0, af, bf); BAR();
      ISS_B_LO(bf, 1, 1); ISS_B_HI(bf, 1, 1);
      if (st) stgB(0, 0, u2);
      WAITL(NFQ); MMX_LO(0, 1, af, bf); WAITL(0); MMX_HI(0, 1, af, bf); BAR();
      ISS_A_LO(af, 1, 1); ISS_A_HI(af, 1, 1);
      if (st) stgA(1, 0, v2);
      WAITL(4); MMX_LO(1, 1, af, bf); WAITL(0); MMX_HI(1, 1, af, bf); BAR();
      ISS_B_LO(bf, 1, 0); ISS_B_HI(bf, 1, 0);
      WAITL(NFQ); MMX_LO(1, 0, af, bf); WAITL(0); MMX_HI(1, 0, af, bf);
      if (st) { VMC(2); }
      BAR();
    }
  } else {
    // ============ pipelined schedule (cross-phase reads, counted lgkm) ========
    f16x8 afX[8], afY[8], bfP[4], bfQ[4];
    stgA(0, 0, 0); stgA(0, 1, 0); stgB(0, 0, 0); stgB(0, 1, 0);
    stgA(1, 0, 1); stgA(1, 1, 1); stgB(1, 0, 1); stgB(1, 1, 1);
    VMC(VPR); BAR();
    ISS_A(afX, 0, 0); ISS_B(bfP, 0, 0);

#pragma unroll 1
    for (int I = 0; I < NI; ++I) {
      const int u2 = 2 * I + 2, v2 = 2 * I + 3;
      const bool st = (I + 1 < NI);
      // p1
      ISS_B(bfQ, 0, 1);
      WAITL(NB); MMX(0, 0, afX, bfP); BAR();
      // p2
      ISS_A(afY, 0, 1);
      if (st) stgA(0, 0, u2);
      WAITL(8); MMX(0, 1, afX, bfQ); BAR();
      // p3
      ISS_B(bfP, 0, 0);
      if (st) stgB(0, 1, u2);
      WAITL(NB); MMX(1, 1, afY, bfQ);
      if (st) { VMC(VP3); } else { VMC(0); }
      BAR();
      // p4
      ISS_A(afX, 1, 0); ISS_B(bfQ, 1, 0);
      if (st) stgA(0, 1, u2);
      WAITL(8 + NB); MMX(1, 0, afY, bfP); BAR();
      // p5
      ISS_B(bfP, 1, 1);
      if (st) stgB(0, 0, u2);
      WAITL(NB); MMX(0, 0, afX, bfQ); BAR();
      // p6
      ISS_A(afY, 1, 1);
      if (st) { stgA(1, 0, v2); stgB(1, 0, v2); }
      WAITL(8); MMX(0, 1, afX, bfP); BAR();
      // p7
      if (st) stgB(1, 1, v2);
      WAITL(0); MMX(1, 1, afY, bfP);
      if (st) { VMC(VP7); }
      BAR();
      // p8
      if (st) {
        ISS_A(afX, 0, 0); ISS_B(bfP, 0, 0);
        stgA(1, 1, v2);
        WAITL(8 + NB);
      } else {
        WAITL(0);
      }
      MMX(1, 0, afY, bfQ); BAR();
    }
  }
#undef ISS_A_LO
#undef ISS_A_HI
#undef ISS_B_LO
#undef ISS_B_HI
#undef ISS_A
#undef ISS_B
#undef MMX_LO
#undef MMX_HI
#undef MMX

  float scl = factor;
  if (scale_ptr != nullptr) scl = factor * scale_ptr[0];
  float* Cb = C + (size_t)bz * S_ * NN;
  const int r0 = bx * 256 + wm * 64 + kq * 4;
  const int c0 = by * BN + wn * (BN / 8) + fr;
#pragma unroll
  for (int mh = 0; mh < 2; ++mh)
#pragma unroll
    for (int nh = 0; nh < 2; ++nh)
#pragma unroll
      for (int m = 0; m < 4; ++m)
#pragma unroll
        for (int n = 0; n < NFQ; ++n)
#pragma unroll
          for (int r = 0; r < 4; ++r)
            Cb[(size_t)(r0 + mh * 128 + m * 16 + r) * NN + c0 + nh * (BN / 2) + n * 16] =
                acc[mh][nh][m][n][r] * scl;
}

// ---------------------------------------------------------------------------
// reductions
// ---------------------------------------------------------------------------
__device__ __forceinline__ float block_reduce_max(float v, float* red, int tid) {
#pragma unroll
  for (int o = 32; o > 0; o >>= 1) v = fmaxf(v, __shfl_xor(v, o, 64));
  __syncthreads();
  if ((tid & 63) == 0) red[tid >> 6] = v;
  __syncthreads();
  return fmaxf(fmaxf(red[0], red[1]), fmaxf(red[2], red[3]));
}
__device__ __forceinline__ float block_reduce_sum(float v, float* red, int tid) {
#pragma unroll
  for (int o = 32; o > 0; o >>= 1) v += __shfl_xor(v, o, 64);
  __syncthreads();
  if ((tid & 63) == 0) red[4 + (tid >> 6)] = v;
  __syncthreads();
  return (red[4] + red[5]) + (red[6] + red[7]);
}

// ---------------------------------------------------------------------------
// K2: row softmax, pad rows folded in (R7/R8-proven).
// ---------------------------------------------------------------------------
__global__ __launch_bounds__(256) void softmax_rows(const float* __restrict__ scores,
                                                    const int* __restrict__ mask,
                                                    const float* __restrict__ qg,
                                                    const float* __restrict__ kg,
                                                    const float* __restrict__ scale_ptr,
                                                    f16* __restrict__ P, int b0) {
  __shared__ float red[8];
  const int q = blockIdx.x, bl = blockIdx.y, bg = b0 + bl;
  const int tid = threadIdx.x;
  const float* srow = scores + ((size_t)bl * S_ + q) * S_;
  f16* prow = P + ((size_t)bl * S_ + q) * S_;
  const int j0 = tid * 8;
  float4 s0v = *(const float4*)(srow + j0);
  float4 s1v = *(const float4*)(srow + j0 + 4);
  float sv[8] = {s0v.x, s0v.y, s0v.z, s0v.w, s1v.x, s1v.y, s1v.z, s1v.w};

  if (mask[bg * S_ + q] == 0) {
    float vv[8];
    float lm = -3.4e38f;
#pragma unroll
    for (int i = 0; i < 8; ++i) {
      vv[i] = sv[i] - NEGC;
      lm = fmaxf(lm, vv[i]);
    }
    float g0 = block_reduce_max(lm, red, tid);
    float lm2 = -3.4e38f;
#pragma unroll 1
    for (int i = 0; i < 8; ++i) {
      float s = sv[i];
      float t = s * (1.0f / 64.0f);
      float rn = rintf(t);
      float dist = (0.5f - fabsf(t - rn)) * 64.0f;
      float v = vv[i];
      if (dist < 1e-3f && v >= g0 - 64.5f) {
        const float* qr = qg + ((size_t)bg * S_ + q) * D_;
        const float* kr = kg + ((size_t)bg * S_ + j0 + i) * D_;
        double acc = 0.0;
        for (int t2 = 0; t2 < D_; ++t2) acc += (double)qr[t2] * (double)kr[t2];
        v = (float)acc * scale_ptr[0] - NEGC;
      }
      vv[i] = v;
      lm2 = fmaxf(lm2, v);
    }
    float gf = block_reduce_max(lm2, red, tid);
    float local = 0.0f;
#pragma unroll
    for (int i = 0; i < 8; ++i) local += (vv[i] == gf) ? 1.0f : 0.0f;
    float cnt = block_reduce_sum(local, red, tid);
    f16 inv = (f16)(1.0f / cnt);
    union { f16 h[8]; uint4 u; } ow;
#pragma unroll
    for (int i = 0; i < 8; ++i) ow.h[i] = (vv[i] == gf) ? inv : (f16)0.0f;
    *(uint4*)(prow + j0) = ow.u;
    return;
  }

  int4 m0 = *(const int4*)(mask + (size_t)bg * S_ + j0);
  int4 m1 = *(const int4*)(mask + (size_t)bg * S_ + j0 + 4);
  int mk[8] = {m0.x, m0.y, m0.z, m0.w, m1.x, m1.y, m1.z, m1.w};
  int fl[8];
  float lm = -3.4e38f;
#pragma unroll
  for (int i = 0; i < 8; ++i) {
    fl[i] = (j0 + i <= q) && (mk[i] != 0);
    if (fl[i]) lm = fmaxf(lm, sv[i]);
  }
  float m = block_reduce_max(lm, red, tid);
  float ls = 0.0f;
#pragma unroll
  for (int i = 0; i < 8; ++i) {
    float e = fl[i] ? expf(sv[i] - m) : 0.0f;
    sv[i] = e; ls += e;
  }
  float sum = block_reduce_sum(ls, red, tid);
  float inv = 1.0f / sum;
  union { f16 h[8]; uint4 u; } ow;
#pragma unroll
  for (int i = 0; i < 8; ++i) ow.h[i] = (f16)(sv[i] * inv);
  *(uint4*)(prow + j0) = ow.u;
}

// ---------------------------------------------------------------------------
extern "C" void kernel_launch(void* const* d_in, const int* in_sizes, int n_in,
                              void* d_out, int out_size, void* d_ws, size_t ws_size,
                              hipStream_t stream) {
  (void)in_sizes; (void)n_in; (void)out_size;
  const float* q = (const float*)d_in[0];
  const float* k = (const float*)d_in[1];
  const int* mask = (const int*)d_in[2];
  const float* scale = (const float*)d_in[3];
  float* out = (float*)d_out;

  const size_t per_qx = (size_t)S_ * KEXP * 2;     // 12.58 MB
  const size_t per_khT = (size_t)D_ * S_ * 2;      //  4.19 MB
  const size_t per_sc = (size_t)S_ * S_ * 4;       // 16.78 MB
  const size_t per_batch = 2 * per_qx + per_khT + per_sc;  // P overlays qx

  int nb = (int)(ws_size / per_batch);
  if (nb > 4) nb = 4;   // 64*nb GEMM blocks: nb=4 -> 256 = exactly 1/CU
  if (nb < 1) nb = 1;

  char* w = (char*)d_ws;
  f16* qx = (f16*)w;
  f16* kx = (f16*)(w + (size_t)nb * per_qx);
  f16* khT = (f16*)(w + (size_t)nb * per_qx * 2);
  float* sc = (float*)(w + (size_t)nb * (per_qx * 2 + per_khT));
  f16* P = qx;                                     // overlay (qx dead post-QK^T)

  for (int b0 = 0; b0 < B_; b0 += nb) {
    int cb = (B_ - b0 < nb) ? (B_ - b0) : nb;
    const float* qb = q + (size_t)b0 * S_ * D_;
    const float* kb = k + (size_t)b0 * S_ * D_;

    int blocks0 = cb * ((S_ * D_ / 8) / 256);  // cb * 1024
    split_expand2<<<dim3(blocks0, 2), dim3(256), 0, stream>>>(qb, kb, qx, kx);
    transpose_cast<<<dim3(S_ / 64, D_ / 64, cb), dim3(256), 0, stream>>>(kb, khT);

    // scores = (q.k) * scale : factor 2^-12 undoes the 64x prescale on q,k
    gemm8p<KEXP, S_, 256, 0><<<dim3(64, cb), dim3(512), 0, stream>>>(
        qx, kx, sc, scale, 0.000244140625f);

    softmax_rows<<<dim3(S_, cb), dim3(256), 0, stream>>>(sc, mask, q, k, scale, P, b0);

    gemm8p<S_, D_, 128, 1><<<dim3(64, cb), dim3(512), 0, stream>>>(
        P, khT, out + (size_t)b0 * S_ * D_, nullptr, 1.0f);
  }
}